// Round 10
// baseline (257.987 us; speedup 1.0000x reference)
//
#include <hip/hip_runtime.h>
#include <math.h>

#define TT 24
#define SS 200
#define CIN 8
#define CW 32
#define NSC 6400      // SS*CW
#define NTOT 153600   // TT*SS*CW
#define NBLK 600

// ws float offsets (cnt in ws[0]; arrays after)
#define XOFF    64
#define M0AOFF  (XOFF  + NTOT)
#define M0BOFF  (M0AOFF + NTOT)
#define M1OFF   (M0BOFF + NTOT)
#define M2OFF   (M1OFF + NTOT)
#define M3OFF   (M2OFF + NTOT)

// Cross-XCD-coherent scalar load (agent scope bypasses the non-coherent
// per-XCD L2 path). R4 proved agent-relaxed atomics observe remote writes
// on this chip. Used ONLY for cross-block-produced arrays (M*, X).
__device__ __forceinline__ float aload(const float* p) {
    return __hip_atomic_load(p, __ATOMIC_RELAXED, __HIP_MEMORY_SCOPE_AGENT);
}

// Grid barrier with NO acquire fence (R3/R4 lesson: acquire = full L2
// invalidate per call = 92 MB refetch storm). Release fence writes back
// this block's dirty lines so consumers' agent-scope loads see them.
// Consumers never invalidate, so read-only inputs stay L2-hot.
__device__ __forceinline__ void gridbar(unsigned* cnt, unsigned target) {
    __syncthreads();
    if (threadIdx.x == 0) {
        __builtin_amdgcn_fence(__ATOMIC_RELEASE, "agent");
        __hip_atomic_fetch_add(cnt, 1u, __ATOMIC_RELAXED, __HIP_MEMORY_SCOPE_AGENT);
        unsigned spins = 0;
        while (__hip_atomic_load(cnt, __ATOMIC_RELAXED, __HIP_MEMORY_SCOPE_AGENT) < target) {
            __builtin_amdgcn_s_sleep(8);
            if (++spins > (1u << 20)) break;   // hang-safety escape
        }
    }
    __syncthreads();
}

__global__ __launch_bounds__(256, 3)
void gtfused(const float* __restrict__ xin, const float* __restrict__ At,
             const float* __restrict__ As, const float* __restrict__ H,
             const float* __restrict__ svec, const float* __restrict__ Wf,
             const float* __restrict__ bf, const float* __restrict__ Wl,
             const float* __restrict__ bl, const float* __restrict__ mW1,
             const float* __restrict__ mb1, const float* __restrict__ mW2,
             const float* __restrict__ mb2, float* __restrict__ out,
             float* __restrict__ ws)
{
    __shared__ float  sd[SS];
    __shared__ float4 sXn[SS], sXd[SS], sU[SS];
    __shared__ float  sdt[TT];
    __shared__ float  sAt[2*TT*TT];
    __shared__ float  sH[3*CW*CW];
    __shared__ float  sW1[(CW+CIN)*CW];
    __shared__ float  sW2[CW*CW];
    __shared__ float  sb1[CW], sb2[CW];
    __shared__ float  sx[256], sp1[256], sp2[256], sxt[256], sh[256];
    __shared__ float  sxin[8*CIN];

    unsigned* cnt = (unsigned*)ws;
    const int tid = threadIdx.x;
    const int bid = blockIdx.x;

    // ---- spatial phase: block (t, cg of 4 ch), thread = s row -------------
    // Computes U1 = As-hat X, U2 = As-hat U1 sequentially (in-LDS), folds
    // into 5 M arrays. first=true also computes X = xin@Wf+bf and dinv_s.
    auto spatial = [&](bool first, int b) {
        if (bid < 192) {
            const int t  = bid >> 3;
            const int c0 = (bid & 7) * 4;
            if (first) {                       // dinv_s: coalesced col sums
                if (tid < SS) {                // (sd persists in LDS for b=1)
                    float sum = 0.f;
                    #pragma unroll 8
                    for (int i = 0; i < SS; ++i) sum += As[i*SS + tid];
                    sd[tid] = 1.f / sqrtf(sum);
                }
            }
            __syncthreads();
            if (tid < SS) {
                float4 xv;
                if (first) {
                    const float4 xa = *(const float4*)(xin + (t*SS + tid)*CIN);
                    const float4 xb = *(const float4*)(xin + (t*SS + tid)*CIN + 4);
                    const float xi[8] = {xa.x,xa.y,xa.z,xa.w,xb.x,xb.y,xb.z,xb.w};
                    xv = *(const float4*)(bf + c0);
                    #pragma unroll
                    for (int i = 0; i < CIN; ++i) {
                        const float4 w = *(const float4*)(Wf + i*CW + c0);
                        xv.x += xi[i]*w.x; xv.y += xi[i]*w.y;
                        xv.z += xi[i]*w.z; xv.w += xi[i]*w.w;
                    }
                    *(float4*)(ws + XOFF + t*NSC + tid*CW + c0) = xv;
                } else {                       // X1 from other blocks: aload
                    const float* xp = ws + XOFF + t*NSC + tid*CW + c0;
                    xv = make_float4(aload(xp), aload(xp+1), aload(xp+2), aload(xp+3));
                }
                sXn[tid] = xv;
                const float d = sd[tid];
                sXd[tid] = make_float4(xv.x*d, xv.y*d, xv.z*d, xv.w*d);
            }
            __syncthreads();
            float4 u1 = make_float4(0.f,0.f,0.f,0.f);
            if (tid < SS) {
                float4 acc = make_float4(0.f,0.f,0.f,0.f);
                #pragma unroll 4
                for (int sp = 0; sp < SS; ++sp) {
                    const float a = As[sp*SS + tid];   // coalesced over tid
                    const float4 x = sXd[sp];          // LDS broadcast
                    acc.x += a*x.x; acc.y += a*x.y; acc.z += a*x.z; acc.w += a*x.w;
                }
                const float h = 0.5f * sd[tid], d = sd[tid];
                u1 = make_float4(acc.x*h, acc.y*h, acc.z*h, acc.w*h);
                sU[tid] = make_float4(u1.x*d, u1.y*d, u1.z*d, u1.w*d);
            }
            __syncthreads();
            if (tid < SS) {
                float4 acc = make_float4(0.f,0.f,0.f,0.f);
                #pragma unroll 4
                for (int sp = 0; sp < SS; ++sp) {
                    const float a = As[sp*SS + tid];
                    const float4 u = sU[sp];
                    acc.x += a*u.x; acc.y += a*u.y; acc.z += a*u.z; acc.w += a*u.w;
                }
                const float h = 0.5f * sd[tid];
                const float4 u2 = make_float4(acc.x*h, acc.y*h, acc.z*h, acc.w*h);
                const float s0 = svec[b*4+0], s1 = svec[b*4+1];
                const float s2 = svec[b*4+2], s3 = svec[b*4+3];
                const float b00 = s0*s0, b01 = 2.f*s0*s1, b02 = s1*s1;
                const float b10 = 2.f*s0*s2, b11 = 2.f*(s0*s3 + s1*s2), b12 = 2.f*s1*s3;
                const float b20 = s2*s2, b21 = 2.f*s2*s3, b22 = s3*s3;
                const float4 xv = sXn[tid];
                const int gid = t*NSC + tid*CW + c0;
                *(float4*)(ws + M0AOFF + gid) = make_float4(
                    s0*xv.x + s1*u1.x, s0*xv.y + s1*u1.y,
                    s0*xv.z + s1*u1.z, s0*xv.w + s1*u1.w);
                *(float4*)(ws + M0BOFF + gid) = make_float4(
                    b00*xv.x + b01*u1.x + b02*u2.x, b00*xv.y + b01*u1.y + b02*u2.y,
                    b00*xv.z + b01*u1.z + b02*u2.z, b00*xv.w + b01*u1.w + b02*u2.w);
                *(float4*)(ws + M1OFF + gid) = make_float4(
                    s2*xv.x + s3*u1.x, s2*xv.y + s3*u1.y,
                    s2*xv.z + s3*u1.z, s2*xv.w + s3*u1.w);
                *(float4*)(ws + M2OFF + gid) = make_float4(
                    b10*xv.x + b11*u1.x + b12*u2.x, b10*xv.y + b11*u1.y + b12*u2.y,
                    b10*xv.z + b11*u1.z + b12*u2.z, b10*xv.w + b11*u1.w + b12*u2.w);
                *(float4*)(ws + M3OFF + gid) = make_float4(
                    b20*xv.x + b21*u1.x + b22*u2.x, b20*xv.y + b21*u1.y + b22*u2.y,
                    b20*xv.z + b21*u1.z + b22*u2.z, b20*xv.w + b21*u1.w + b22*u2.w);
            }
        }
    };

    // ---- temporal + epilogue phase: block (t, sg of 8 rows), all 32 ch ----
    auto kbphase = [&](int b, bool last) {
        if (b == 0) {                          // local At-hat / At-hat^2 prep
            if (tid < TT) {
                float sum = 0.f;
                #pragma unroll
                for (int j = 0; j < TT; ++j) sum += At[j*TT + tid];
                sdt[tid] = 1.f / sqrtf(sum);
            }
            __syncthreads();
            for (int i = tid; i < TT*TT; i += 256)
                sAt[i] = At[i] * sdt[i/TT] * sdt[i%TT] * 0.5f;
            __syncthreads();
            for (int i = tid; i < TT*TT; i += 256) {
                const int r = i / TT, cc = i % TT;
                float acc = 0.f;
                #pragma unroll
                for (int k = 0; k < TT; ++k) acc += sAt[r*TT + k] * sAt[k*TT + cc];
                sAt[TT*TT + i] = acc;
            }
        }
        for (int i = tid; i < 3*CW*CW; i += 256) sH[i] = H[b*3*CW*CW + i];
        for (int i = tid; i < (CW+CIN)*CW; i += 256) sW1[i] = mW1[b*(CW+CIN)*CW + i];
        for (int i = tid; i < CW*CW; i += 256) sW2[i] = mW2[b*CW*CW + i];
        if (tid < CW) { sb1[tid] = mb1[b*CW + tid]; sb2[tid] = mb2[b*CW + tid]; }

        const int gid = bid*256 + tid;
        const int t = gid / NSC;
        const int sc = gid - t*NSC;
        const int r = tid >> 5, c = tid & 31;
        const int node = gid >> 5;
        // b=0: X from spatial blocks (cross-block -> aload).
        // b=1: X1 written by THIS block in phase 2 -> normal load.
        sx[tid] = last ? ws[XOFF + gid] : aload(ws + XOFF + gid);
        if (c < CIN) sxin[r*CIN + c] = xin[node*CIN + c];
        __syncthreads();
        {
            const float* M1 = ws + M1OFF + sc;
            const float* M2 = ws + M2OFF + sc;
            const float* M3 = ws + M3OFF + sc;
            float d1 = 0.f, d2 = 0.f, d3 = 0.f;
            #pragma unroll
            for (int tp = 0; tp < TT; ++tp) {
                const float a1 = sAt[t*TT + tp];
                const float a2 = sAt[TT*TT + t*TT + tp];
                d1 += a1 * aload(M1 + tp*NSC);
                d2 += a1 * aload(M2 + tp*NSC);
                d3 += a2 * aload(M3 + tp*NSC);
            }
            sp1[tid] = aload(ws + M0AOFF + gid) + d1;
            sp2[tid] = aload(ws + M0BOFF + gid) + d2 + d3;
        }
        __syncthreads();
        {
            float acc = 0.f;
            #pragma unroll 8
            for (int cp = 0; cp < CW; ++cp) {
                acc += sx[r*CW + cp]  * sH[cp*CW + c];
                acc += sp1[r*CW + cp] * sH[CW*CW + cp*CW + c];
                acc += sp2[r*CW + cp] * sH[2*CW*CW + cp*CW + c];
            }
            sxt[tid] = tanhf(acc);
        }
        __syncthreads();
        {
            float h = sb1[c];
            #pragma unroll 8
            for (int cp = 0; cp < CW; ++cp) h += sxt[r*CW + cp] * sW1[cp*CW + c];
            #pragma unroll
            for (int i = 0; i < CIN; ++i) h += sxin[r*CIN + i] * sW1[(CW+i)*CW + c];
            sh[tid] = fmaxf(h, 0.f);
        }
        __syncthreads();
        {
            float xn = sb2[c];
            #pragma unroll 8
            for (int cp = 0; cp < CW; ++cp) xn += sh[r*CW + cp] * sW2[cp*CW + c];
            if (!last) {
                ws[XOFF + gid] = xn;
            } else {
                float v = xn * Wl[c];
                #pragma unroll
                for (int off = 16; off; off >>= 1) v += __shfl_xor(v, off, 64);
                if (c == 0) out[node] = v + bl[0];
            }
        }
        __syncthreads();
    };

    spatial(true, 0);
    gridbar(cnt, NBLK);
    kbphase(0, false);
    gridbar(cnt, 2u*NBLK);
    spatial(false, 1);
    gridbar(cnt, 3u*NBLK);
    kbphase(1, true);
}

extern "C" void kernel_launch(void* const* d_in, const int* in_sizes, int n_in,
                              void* d_out, int out_size, void* d_ws, size_t ws_size,
                              hipStream_t stream) {
    const float* xin   = (const float*)d_in[0];
    const float* Adj_t = (const float*)d_in[1];
    const float* Adj_s = (const float*)d_in[2];
    const float* H     = (const float*)d_in[3];
    const float* svec  = (const float*)d_in[4];
    const float* Wf    = (const float*)d_in[5];
    const float* bf    = (const float*)d_in[6];
    const float* Wl    = (const float*)d_in[7];
    const float* bl    = (const float*)d_in[8];
    const float* mW1   = (const float*)d_in[9];
    const float* mb1   = (const float*)d_in[10];
    const float* mW2   = (const float*)d_in[11];
    const float* mb2   = (const float*)d_in[12];
    float* out = (float*)d_out;
    float* ws  = (float*)d_ws;

    hipMemsetAsync(d_ws, 0, 256, stream);   // zero barrier counter each call
    gtfused<<<NBLK, 256, 0, stream>>>(xin, Adj_t, Adj_s, H, svec, Wf, bf,
                                      Wl, bl, mW1, mb1, mW2, mb2, out, ws);
}

// Round 11
// 122.621 us; speedup vs baseline: 2.1039x; 2.1039x over previous
//
#include <hip/hip_runtime.h>
#include <math.h>

#define TT 24
#define SS 200
#define CIN 8
#define CW 32
#define NSC 6400      // SS*CW
#define NTOT 153600   // TT*SS*CW

// ws float offsets
#define DSOFF  0          // dinv_s [200]
#define ATOFF  256        // At-hat [576]
#define AT2OFF 832        // At-hat^2 [576]
#define XOFF   1408       // X  [NTOT]
#define X1OFF  (XOFF  + NTOT)
#define M0A0   (X1OFF + NTOT)
#define M0B0   (M0A0 + NTOT)
#define M10    (M0B0 + NTOT)
#define M20    (M10  + NTOT)
#define M30    (M20  + NTOT)
#define M0A1   (M30  + NTOT)
#define M0B1   (M0A1 + NTOT)
#define M11    (M0B1 + NTOT)
#define M21    (M11  + NTOT)
#define M31    (M21  + NTOT)   // end = 1408 + 12*NTOT ~ 7.4 MB

// ---------------- D1: X = xin@Wf+bf, spatial(b0) -> M(b0); block192 At prep
__global__ __launch_bounds__(1024)
void kSp0(const float* __restrict__ xin, const float* __restrict__ At,
          const float* __restrict__ As, const float* __restrict__ Wf,
          const float* __restrict__ bf, const float* __restrict__ svec,
          float* __restrict__ ws)
{
    __shared__ float4 sXd[SS], sXn[SS], sU[SS], spart[4][SS];
    __shared__ float  sd[256], sdt[TT], sAt[TT*TT];
    const int tid = threadIdx.x;

    if (blockIdx.x == 192) {           // At-hat / At-hat^2 prep
        if (tid < TT) {
            float sum = 0.f;
            #pragma unroll
            for (int i = 0; i < TT; ++i) sum += At[i*TT + tid];
            sdt[tid] = 1.f / sqrtf(sum);
        }
        __syncthreads();
        if (tid < TT*TT) {
            const int i = tid / TT, j = tid % TT;
            const float v = At[tid] * sdt[i] * sdt[j] * 0.5f;
            sAt[tid] = v;
            ws[ATOFF + tid] = v;
        }
        __syncthreads();
        if (tid < TT*TT) {
            const int i = tid / TT, j = tid % TT;
            float acc = 0.f;
            #pragma unroll
            for (int k = 0; k < TT; ++k) acc += sAt[i*TT + k] * sAt[k*TT + j];
            ws[AT2OFF + tid] = acc;
        }
        return;
    }

    const int q = tid >> 8;            // sp quarter
    const int s = tid & 255;
    const bool act = s < SS;
    const int t  = blockIdx.x >> 3;
    const int c0 = (blockIdx.x & 7) * 4;

    if (tid < SS) {                    // dinv_s: coalesced column sums
        float sum = 0.f;
        #pragma unroll 8
        for (int i = 0; i < SS; ++i) sum += As[i*SS + tid];
        const float d = 1.f / sqrtf(sum);
        sd[tid] = d;
        if (blockIdx.x == 0) ws[DSOFF + tid] = d;
    }
    __syncthreads();

    if (tid < SS) {                    // X = xin@Wf + bf for (t, s, c0..c0+3)
        const float4 xa = *(const float4*)(xin + (t*SS + tid)*CIN);
        const float4 xb = *(const float4*)(xin + (t*SS + tid)*CIN + 4);
        const float xi[8] = {xa.x,xa.y,xa.z,xa.w,xb.x,xb.y,xb.z,xb.w};
        float4 xv = *(const float4*)(bf + c0);
        #pragma unroll
        for (int i = 0; i < CIN; ++i) {
            const float4 w = *(const float4*)(Wf + i*CW + c0);
            xv.x += xi[i]*w.x; xv.y += xi[i]*w.y;
            xv.z += xi[i]*w.z; xv.w += xi[i]*w.w;
        }
        *(float4*)(ws + XOFF + t*NSC + tid*CW + c0) = xv;
        sXn[tid] = xv;
        const float d = sd[tid];
        sXd[tid] = make_float4(xv.x*d, xv.y*d, xv.z*d, xv.w*d);
    }
    __syncthreads();

    float4 u1 = make_float4(0.f,0.f,0.f,0.f);
    if (act) {
        float4 acc = make_float4(0.f,0.f,0.f,0.f);
        #pragma unroll 5
        for (int sp = q*50; sp < q*50 + 50; ++sp) {
            const float a = As[sp*SS + s];
            const float4 x = sXd[sp];
            acc.x += a*x.x; acc.y += a*x.y; acc.z += a*x.z; acc.w += a*x.w;
        }
        spart[q][s] = acc;
    }
    __syncthreads();
    if (q == 0 && act) {
        const float4 p0 = spart[0][s], p1 = spart[1][s];
        const float4 p2 = spart[2][s], p3 = spart[3][s];
        const float h = 0.5f * sd[s], d = sd[s];
        u1 = make_float4((p0.x+p1.x+p2.x+p3.x)*h, (p0.y+p1.y+p2.y+p3.y)*h,
                         (p0.z+p1.z+p2.z+p3.z)*h, (p0.w+p1.w+p2.w+p3.w)*h);
        sU[s] = make_float4(u1.x*d, u1.y*d, u1.z*d, u1.w*d);
    }
    __syncthreads();
    if (act) {
        float4 acc = make_float4(0.f,0.f,0.f,0.f);
        #pragma unroll 5
        for (int sp = q*50; sp < q*50 + 50; ++sp) {
            const float a = As[sp*SS + s];
            const float4 u = sU[sp];
            acc.x += a*u.x; acc.y += a*u.y; acc.z += a*u.z; acc.w += a*u.w;
        }
        spart[q][s] = acc;
    }
    __syncthreads();
    if (q == 0 && act) {
        const float4 p0 = spart[0][s], p1 = spart[1][s];
        const float4 p2 = spart[2][s], p3 = spart[3][s];
        const float h = 0.5f * sd[s];
        const float4 u2 = make_float4((p0.x+p1.x+p2.x+p3.x)*h, (p0.y+p1.y+p2.y+p3.y)*h,
                                      (p0.z+p1.z+p2.z+p3.z)*h, (p0.w+p1.w+p2.w+p3.w)*h);
        const float s0 = svec[0], s1 = svec[1], s2 = svec[2], s3 = svec[3];
        const float b00 = s0*s0, b01 = 2.f*s0*s1, b02 = s1*s1;
        const float b10 = 2.f*s0*s2, b11 = 2.f*(s0*s3 + s1*s2), b12 = 2.f*s1*s3;
        const float b20 = s2*s2, b21 = 2.f*s2*s3, b22 = s3*s3;
        const float4 xv = sXn[s];
        const int g4 = t*NSC + s*CW + c0;
        *(float4*)(ws + M0A0 + g4) = make_float4(
            s0*xv.x + s1*u1.x, s0*xv.y + s1*u1.y,
            s0*xv.z + s1*u1.z, s0*xv.w + s1*u1.w);
        *(float4*)(ws + M0B0 + g4) = make_float4(
            b00*xv.x + b01*u1.x + b02*u2.x, b00*xv.y + b01*u1.y + b02*u2.y,
            b00*xv.z + b01*u1.z + b02*u2.z, b00*xv.w + b01*u1.w + b02*u2.w);
        *(float4*)(ws + M10 + g4) = make_float4(
            s2*xv.x + s3*u1.x, s2*xv.y + s3*u1.y,
            s2*xv.z + s3*u1.z, s2*xv.w + s3*u1.w);
        *(float4*)(ws + M20 + g4) = make_float4(
            b10*xv.x + b11*u1.x + b12*u2.x, b10*xv.y + b11*u1.y + b12*u2.y,
            b10*xv.z + b11*u1.z + b12*u2.z, b10*xv.w + b11*u1.w + b12*u2.w);
        *(float4*)(ws + M30 + g4) = make_float4(
            b20*xv.x + b21*u1.x + b22*u2.x, b20*xv.y + b21*u1.y + b22*u2.y,
            b20*xv.z + b21*u1.z + b22*u2.z, b20*xv.w + b21*u1.w + b22*u2.w);
    }
}

// ---------------- D2: temporal(b0)+epilogue(b0) for slab t, spatial(b1) -----
// 96 blocks = 24 slabs x 4 parts; each part duplicates A (temporal+epilogue,
// cheap) and does spatial(b1) for its 8-channel strip (parallelism back).
__global__ __launch_bounds__(1024, 1)
void kMid(const float* __restrict__ xin, const float* __restrict__ As,
          const float* __restrict__ H, const float* __restrict__ svec,
          const float* __restrict__ mW1, const float* __restrict__ mb1,
          const float* __restrict__ mW2, const float* __restrict__ mb2,
          float* __restrict__ ws)
{
    __shared__ float  sAtr[TT], sAt2r[TT];
    __shared__ float  sH[3*CW*CW], sW1[(CW+CIN)*CW], sW2[CW*CW];
    __shared__ float  sb1[CW], sb2[CW];
    __shared__ float  sd[256];
    __shared__ float  sx[NSC], sp1[NSC], sp2[NSC];     // 3 x 25.6 KB
    __shared__ float  sxt_l[1024], sh_l[1024];
    __shared__ float  sxin[32*CIN];
    __shared__ float4 sXd[SS], sU[SS], spart[4][SS];

    const int tid  = threadIdx.x;
    const int t    = blockIdx.x >> 2;
    const int part = blockIdx.x & 3;

    // ---- staging ----
    for (int i = tid; i < 3*CW*CW; i += 1024) sH[i] = H[i];              // b0
    for (int i = tid; i < (CW+CIN)*CW; i += 1024) sW1[i] = mW1[i];
    for (int i = tid; i < CW*CW; i += 1024) sW2[i] = mW2[i];
    if (tid < CW) { sb1[tid] = mb1[tid]; sb2[tid] = mb2[tid]; }
    if (tid < TT) { sAtr[tid] = ws[ATOFF + t*TT + tid];
                    sAt2r[tid] = ws[AT2OFF + t*TT + tid]; }
    if (tid < SS) sd[tid] = ws[DSOFF + tid];
    __syncthreads();

    // ---- phase A: p1/p2 for slab t (float4 over sc) ----
    for (int i = tid; i < NSC/4; i += 1024) {
        float4 d1 = make_float4(0,0,0,0), d2 = d1, d3 = d1;
        #pragma unroll
        for (int tp = 0; tp < TT; ++tp) {
            const float a1 = sAtr[tp], a2 = sAt2r[tp];
            const float4 m1 = *((const float4*)(ws + M10) + tp*(NSC/4) + i);
            const float4 m2 = *((const float4*)(ws + M20) + tp*(NSC/4) + i);
            const float4 m3 = *((const float4*)(ws + M30) + tp*(NSC/4) + i);
            d1.x += a1*m1.x; d1.y += a1*m1.y; d1.z += a1*m1.z; d1.w += a1*m1.w;
            d2.x += a1*m2.x; d2.y += a1*m2.y; d2.z += a1*m2.z; d2.w += a1*m2.w;
            d3.x += a2*m3.x; d3.y += a2*m3.y; d3.z += a2*m3.z; d3.w += a2*m3.w;
        }
        const float4 m0a = *((const float4*)(ws + M0A0) + t*(NSC/4) + i);
        const float4 m0b = *((const float4*)(ws + M0B0) + t*(NSC/4) + i);
        const float4 xv  = *((const float4*)(ws + XOFF) + t*(NSC/4) + i);
        *(float4*)(sp1 + 4*i) = make_float4(m0a.x+d1.x, m0a.y+d1.y, m0a.z+d1.z, m0a.w+d1.w);
        *(float4*)(sp2 + 4*i) = make_float4(m0b.x+d2.x+d3.x, m0b.y+d2.y+d3.y,
                                            m0b.z+d2.z+d3.z, m0b.w+d2.w+d3.w);
        *(float4*)(sx + 4*i) = xv;
    }
    __syncthreads();

    // ---- epilogue (b0): chunks of 32 nodes x 32 ch; x1 overwrites sp1 ----
    for (int k = 0; k < 7; ++k) {
        const int nl = tid >> 5, c = tid & 31;
        const int node = k*32 + nl;
        const bool on = node < SS;
        if (on && c < CIN) sxin[nl*CIN + c] = xin[(t*SS + node)*CIN + c];
        __syncthreads();
        float xt = 0.f;
        if (on) {
            float acc = 0.f;
            #pragma unroll 8
            for (int cp = 0; cp < CW; ++cp) {
                acc += sx[node*CW + cp]  * sH[cp*CW + c];
                acc += sp1[node*CW + cp] * sH[CW*CW + cp*CW + c];
                acc += sp2[node*CW + cp] * sH[2*CW*CW + cp*CW + c];
            }
            xt = tanhf(acc);
        }
        sxt_l[tid] = xt;
        __syncthreads();
        float hv = 0.f;
        if (on) {
            float h = sb1[c];
            #pragma unroll 8
            for (int cp = 0; cp < CW; ++cp) h += sxt_l[nl*CW + cp] * sW1[cp*CW + c];
            #pragma unroll
            for (int i = 0; i < CIN; ++i) h += sxin[nl*CIN + i] * sW1[(CW+i)*CW + c];
            hv = fmaxf(h, 0.f);
        }
        sh_l[tid] = hv;
        __syncthreads();
        float xn = 0.f;
        if (on) {
            xn = sb2[c];
            #pragma unroll 8
            for (int cp = 0; cp < CW; ++cp) xn += sh_l[nl*CW + cp] * sW2[cp*CW + c];
        }
        __syncthreads();
        if (on) {
            sp1[node*CW + c] = xn;        // x1 (aliases p1 space, reads done)
            if (part == 0) ws[X1OFF + t*NSC + node*CW + c] = xn;
        }
        __syncthreads();
    }

    // ---- phase B: spatial(b1) for channels part*8 .. part*8+7 ----
    const int q = tid >> 8, s = tid & 255;
    const bool act = s < SS;
    const float s0 = svec[4], s1 = svec[5], s2 = svec[6], s3 = svec[7];
    const float b00 = s0*s0, b01 = 2.f*s0*s1, b02 = s1*s1;
    const float b10 = 2.f*s0*s2, b11 = 2.f*(s0*s3 + s1*s2), b12 = 2.f*s1*s3;
    const float b20 = s2*s2, b21 = 2.f*s2*s3, b22 = s3*s3;

    for (int g = 0; g < 2; ++g) {
        const int c0 = part*8 + g*4;
        if (q == 0 && act) {
            const float4 xv = *(const float4*)(sp1 + s*CW + c0);
            const float d = sd[s];
            sXd[s] = make_float4(xv.x*d, xv.y*d, xv.z*d, xv.w*d);
        }
        __syncthreads();
        float4 u1 = make_float4(0.f,0.f,0.f,0.f);
        if (act) {
            float4 acc = make_float4(0.f,0.f,0.f,0.f);
            #pragma unroll 5
            for (int sp = q*50; sp < q*50 + 50; ++sp) {
                const float a = As[sp*SS + s];
                const float4 x = sXd[sp];
                acc.x += a*x.x; acc.y += a*x.y; acc.z += a*x.z; acc.w += a*x.w;
            }
            spart[q][s] = acc;
        }
        __syncthreads();
        if (q == 0 && act) {
            const float4 p0 = spart[0][s], p1 = spart[1][s];
            const float4 p2 = spart[2][s], p3 = spart[3][s];
            const float h = 0.5f * sd[s], d = sd[s];
            u1 = make_float4((p0.x+p1.x+p2.x+p3.x)*h, (p0.y+p1.y+p2.y+p3.y)*h,
                             (p0.z+p1.z+p2.z+p3.z)*h, (p0.w+p1.w+p2.w+p3.w)*h);
            sU[s] = make_float4(u1.x*d, u1.y*d, u1.z*d, u1.w*d);
        }
        __syncthreads();
        if (act) {
            float4 acc = make_float4(0.f,0.f,0.f,0.f);
            #pragma unroll 5
            for (int sp = q*50; sp < q*50 + 50; ++sp) {
                const float a = As[sp*SS + s];
                const float4 u = sU[sp];
                acc.x += a*u.x; acc.y += a*u.y; acc.z += a*u.z; acc.w += a*u.w;
            }
            spart[q][s] = acc;
        }
        __syncthreads();
        if (q == 0 && act) {
            const float4 p0 = spart[0][s], p1 = spart[1][s];
            const float4 p2 = spart[2][s], p3 = spart[3][s];
            const float h = 0.5f * sd[s];
            const float4 u2 = make_float4((p0.x+p1.x+p2.x+p3.x)*h, (p0.y+p1.y+p2.y+p3.y)*h,
                                          (p0.z+p1.z+p2.z+p3.z)*h, (p0.w+p1.w+p2.w+p3.w)*h);
            const float4 xv = *(const float4*)(sp1 + s*CW + c0);
            const int g4 = t*NSC + s*CW + c0;
            *(float4*)(ws + M0A1 + g4) = make_float4(
                s0*xv.x + s1*u1.x, s0*xv.y + s1*u1.y,
                s0*xv.z + s1*u1.z, s0*xv.w + s1*u1.w);
            *(float4*)(ws + M0B1 + g4) = make_float4(
                b00*xv.x + b01*u1.x + b02*u2.x, b00*xv.y + b01*u1.y + b02*u2.y,
                b00*xv.z + b01*u1.z + b02*u2.z, b00*xv.w + b01*u1.w + b02*u2.w);
            *(float4*)(ws + M11 + g4) = make_float4(
                s2*xv.x + s3*u1.x, s2*xv.y + s3*u1.y,
                s2*xv.z + s3*u1.z, s2*xv.w + s3*u1.w);
            *(float4*)(ws + M21 + g4) = make_float4(
                b10*xv.x + b11*u1.x + b12*u2.x, b10*xv.y + b11*u1.y + b12*u2.y,
                b10*xv.z + b11*u1.z + b12*u2.z, b10*xv.w + b11*u1.w + b12*u2.w);
            *(float4*)(ws + M31 + g4) = make_float4(
                b20*xv.x + b21*u1.x + b22*u2.x, b20*xv.y + b21*u1.y + b22*u2.y,
                b20*xv.z + b21*u1.z + b22*u2.z, b20*xv.w + b21*u1.w + b22*u2.w);
        }
        __syncthreads();
    }
}

// ---------------- D3: temporal(b1) + epilogue(b1) + final out ---------------
__global__ __launch_bounds__(256)
void kBlast(const float* __restrict__ xin, const float* __restrict__ H,
            const float* __restrict__ mW1, const float* __restrict__ mb1,
            const float* __restrict__ mW2, const float* __restrict__ mb2,
            const float* __restrict__ Wl, const float* __restrict__ bl,
            float* __restrict__ ws, float* __restrict__ out) {
    __shared__ float sAt[2*TT*TT];
    __shared__ float sH[3*CW*CW];
    __shared__ float sW1[(CW+CIN)*CW];
    __shared__ float sW2[CW*CW];
    __shared__ float sb1[CW], sb2[CW];
    __shared__ float sx[256], sp1[256], sp2[256], sxt[256], sh[256];
    __shared__ float sxin[8*CIN];

    const int tid = threadIdx.x;
    const int gid = blockIdx.x*256 + tid;
    const int t = gid / NSC;
    const int sc = gid - t*NSC;
    const int r = tid >> 5, c = tid & 31;
    const int node = gid >> 5;

    for (int i = tid; i < 2*TT*TT; i += 256) sAt[i] = ws[ATOFF + i];
    for (int i = tid; i < 3*CW*CW; i += 256) sH[i] = H[3*CW*CW + i];         // b1
    for (int i = tid; i < (CW+CIN)*CW; i += 256) sW1[i] = mW1[(CW+CIN)*CW + i];
    for (int i = tid; i < CW*CW; i += 256) sW2[i] = mW2[CW*CW + i];
    if (tid < CW) { sb1[tid] = mb1[CW + tid]; sb2[tid] = mb2[CW + tid]; }
    sx[tid] = ws[X1OFF + gid];
    if (c < CIN) sxin[r*CIN + c] = xin[node*CIN + c];
    __syncthreads();

    {
        const float* M1 = ws + M11 + sc;
        const float* M2 = ws + M21 + sc;
        const float* M3 = ws + M31 + sc;
        float d1 = 0.f, d2 = 0.f, d3 = 0.f;
        #pragma unroll
        for (int tp = 0; tp < TT; ++tp) {
            const float a1 = sAt[t*TT + tp];
            const float a2 = sAt[TT*TT + t*TT + tp];
            d1 += a1 * M1[tp*NSC];
            d2 += a1 * M2[tp*NSC];
            d3 += a2 * M3[tp*NSC];
        }
        sp1[tid] = ws[M0A1 + gid] + d1;
        sp2[tid] = ws[M0B1 + gid] + d2 + d3;
    }
    __syncthreads();
    {
        float acc = 0.f;
        #pragma unroll 8
        for (int cp = 0; cp < CW; ++cp) {
            acc += sx[r*CW + cp]  * sH[cp*CW + c];
            acc += sp1[r*CW + cp] * sH[CW*CW + cp*CW + c];
            acc += sp2[r*CW + cp] * sH[2*CW*CW + cp*CW + c];
        }
        sxt[tid] = tanhf(acc);
    }
    __syncthreads();
    {
        float h = sb1[c];
        #pragma unroll 8
        for (int cp = 0; cp < CW; ++cp) h += sxt[r*CW + cp] * sW1[cp*CW + c];
        #pragma unroll
        for (int i = 0; i < CIN; ++i) h += sxin[r*CIN + i] * sW1[(CW+i)*CW + c];
        sh[tid] = fmaxf(h, 0.f);
    }
    __syncthreads();
    {
        float xn = sb2[c];
        #pragma unroll 8
        for (int cp = 0; cp < CW; ++cp) xn += sh[r*CW + cp] * sW2[cp*CW + c];
        float v = xn * Wl[c];
        #pragma unroll
        for (int off = 16; off; off >>= 1) v += __shfl_xor(v, off, 64);
        if (c == 0) out[node] = v + bl[0];
    }
}

extern "C" void kernel_launch(void* const* d_in, const int* in_sizes, int n_in,
                              void* d_out, int out_size, void* d_ws, size_t ws_size,
                              hipStream_t stream) {
    const float* xin   = (const float*)d_in[0];
    const float* Adj_t = (const float*)d_in[1];
    const float* Adj_s = (const float*)d_in[2];
    const float* H     = (const float*)d_in[3];
    const float* svec  = (const float*)d_in[4];
    const float* Wf    = (const float*)d_in[5];
    const float* bf    = (const float*)d_in[6];
    const float* Wl    = (const float*)d_in[7];
    const float* bl    = (const float*)d_in[8];
    const float* mW1   = (const float*)d_in[9];
    const float* mb1   = (const float*)d_in[10];
    const float* mW2   = (const float*)d_in[11];
    const float* mb2   = (const float*)d_in[12];
    float* out = (float*)d_out;
    float* ws  = (float*)d_ws;

    kSp0<<<193, 1024, 0, stream>>>(xin, Adj_t, Adj_s, Wf, bf, svec, ws);
    kMid<<<96, 1024, 0, stream>>>(xin, Adj_s, H, svec, mW1, mb1, mW2, mb2, ws);
    kBlast<<<600, 256, 0, stream>>>(xin, H, mW1, mb1, mW2, mb2, Wl, bl, ws, out);
}

// Round 12
// 57.944 us; speedup vs baseline: 4.4524x; 2.1162x over previous
//
#include <hip/hip_runtime.h>
#include <math.h>

#define TT 24
#define SS 200
#define CIN 8
#define CW 32
#define NSC 6400      // SS*CW
#define NTOT 153600   // TT*SS*CW

// ws float offsets
#define DSOFF    0        // dinv_s [200]
#define ATOFF    256      // At-hat [576]
#define AT2OFF   832      // At-hat^2 [576]
#define XOFF     1408     // X (in-place X0 -> X1) [NTOT]
#define PM123OFF 155008   // float4[(t*NSC+sc)] = (M1,M2,M3,0)  [4*NTOT]
#define PM0OFF   769408   // float2[(t*NSC+sc)] = (M0A,M0B)     [2*NTOT]
                          // end 1076608 floats ~4.31 MB

// ---------------- kSp: spatial passes, one block = (t, 4-channel group) ----
// U1 = As-hat X, U2 = As-hat U1 sequentially in-block. Writes PACKED
// M-arrays: PM123 float4 (kB reads 24 b128 loads instead of 72 b32),
// PM0 float2. FIRST also computes X = xin@Wf+bf; block 192 At prep.
template<bool FIRST>
__global__ __launch_bounds__(1024)
void kSp(const float* __restrict__ xin, const float* __restrict__ At,
         const float* __restrict__ As, const float* __restrict__ Wf,
         const float* __restrict__ bf, const float* __restrict__ svec,
         float* __restrict__ ws, int b)
{
    __shared__ float4 sXd[SS];        // d_sp * X[sp, c0..c0+3]
    __shared__ float4 sXn[SS];        // X
    __shared__ float4 sU[SS];         // d_s * U1
    __shared__ float4 spart[4][SS];   // partial sums
    __shared__ float  sd[256];
    __shared__ float  sdt[TT];
    __shared__ float  sAt[TT*TT];

    const int tid = threadIdx.x;

    if (FIRST && blockIdx.x == 192) {  // At-hat / At-hat^2 prep
        if (tid < TT) {
            float sum = 0.f;
            #pragma unroll
            for (int i = 0; i < TT; ++i) sum += At[i*TT + tid];
            sdt[tid] = 1.f / sqrtf(sum);
        }
        __syncthreads();
        if (tid < TT*TT) {
            const int i = tid / TT, j = tid % TT;
            const float v = At[tid] * sdt[i] * sdt[j] * 0.5f;
            sAt[tid] = v;
            ws[ATOFF + tid] = v;
        }
        __syncthreads();
        if (tid < TT*TT) {
            const int i = tid / TT, j = tid % TT;
            float acc = 0.f;
            #pragma unroll
            for (int k = 0; k < TT; ++k) acc += sAt[i*TT + k] * sAt[k*TT + j];
            ws[AT2OFF + tid] = acc;
        }
        return;
    }

    const int q = tid >> 8;          // 0..3 (sp quarter)
    const int s = tid & 255;         // spatial row; active if <200
    const bool act = s < SS;
    const int t  = blockIdx.x >> 3;
    const int c0 = (blockIdx.x & 7) * 4;

    // ---- dinv_s ----
    if (FIRST) {
        if (tid < SS) {              // coalesced column sums (As symmetric)
            float sum = 0.f;
            #pragma unroll 8
            for (int i = 0; i < SS; ++i) sum += As[i*SS + tid];
            const float d = 1.f / sqrtf(sum);
            sd[tid] = d;
            if (blockIdx.x == 0) ws[DSOFF + tid] = d;
        }
    } else {
        if (tid < SS) sd[tid] = ws[DSOFF + tid];
    }
    __syncthreads();

    // ---- stage X (+ compute it if FIRST) ----
    if (tid < SS) {
        float4 xv;
        if (FIRST) {
            const float4 xa = *(const float4*)(xin + (t*SS + tid)*CIN);
            const float4 xb = *(const float4*)(xin + (t*SS + tid)*CIN + 4);
            const float xi[8] = {xa.x,xa.y,xa.z,xa.w,xb.x,xb.y,xb.z,xb.w};
            xv = *(const float4*)(bf + c0);
            #pragma unroll
            for (int i = 0; i < CIN; ++i) {
                const float4 w = *(const float4*)(Wf + i*CW + c0);
                xv.x += xi[i]*w.x; xv.y += xi[i]*w.y;
                xv.z += xi[i]*w.z; xv.w += xi[i]*w.w;
            }
            *(float4*)(ws + XOFF + t*NSC + tid*CW + c0) = xv;
        } else {
            xv = *(const float4*)(ws + XOFF + t*NSC + tid*CW + c0);
        }
        sXn[tid] = xv;
        const float d = sd[tid];
        sXd[tid] = make_float4(xv.x*d, xv.y*d, xv.z*d, xv.w*d);
    }
    __syncthreads();

    // ---- U1 = 0.5 d_s sum_sp As[sp,s] * (d_sp X[sp,:]) ----
    float4 u1 = make_float4(0.f, 0.f, 0.f, 0.f);
    if (act) {
        float4 acc = make_float4(0.f, 0.f, 0.f, 0.f);
        #pragma unroll 5
        for (int sp = q*50; sp < q*50 + 50; ++sp) {
            const float a = As[sp*SS + s];
            const float4 xd = sXd[sp];
            acc.x += a*xd.x; acc.y += a*xd.y; acc.z += a*xd.z; acc.w += a*xd.w;
        }
        spart[q][s] = acc;
    }
    __syncthreads();
    if (q == 0 && act) {
        const float4 p0 = spart[0][s], p1 = spart[1][s];
        const float4 p2 = spart[2][s], p3 = spart[3][s];
        const float h = 0.5f * sd[s], d = sd[s];
        u1 = make_float4((p0.x+p1.x+p2.x+p3.x)*h, (p0.y+p1.y+p2.y+p3.y)*h,
                         (p0.z+p1.z+p2.z+p3.z)*h, (p0.w+p1.w+p2.w+p3.w)*h);
        sU[s] = make_float4(u1.x*d, u1.y*d, u1.z*d, u1.w*d);
    }
    __syncthreads();

    // ---- U2 = 0.5 d_s sum_sp As[sp,s] * (d_sp U1[sp,:]) ----
    if (act) {
        float4 acc = make_float4(0.f, 0.f, 0.f, 0.f);
        #pragma unroll 5
        for (int sp = q*50; sp < q*50 + 50; ++sp) {
            const float a = As[sp*SS + s];
            const float4 ud = sU[sp];
            acc.x += a*ud.x; acc.y += a*ud.y; acc.z += a*ud.z; acc.w += a*ud.w;
        }
        spart[q][s] = acc;
    }
    __syncthreads();
    if (q == 0 && act) {
        const float4 p0 = spart[0][s], p1 = spart[1][s];
        const float4 p2 = spart[2][s], p3 = spart[3][s];
        const float h = 0.5f * sd[s];
        const float4 u2 = make_float4((p0.x+p1.x+p2.x+p3.x)*h, (p0.y+p1.y+p2.y+p3.y)*h,
                                      (p0.z+p1.z+p2.z+p3.z)*h, (p0.w+p1.w+p2.w+p3.w)*h);
        const float s0 = svec[b*4+0], s1 = svec[b*4+1];
        const float s2 = svec[b*4+2], s3 = svec[b*4+3];
        const float b00 = s0*s0, b01 = 2.f*s0*s1, b02 = s1*s1;
        const float b10 = 2.f*s0*s2, b11 = 2.f*(s0*s3 + s1*s2), b12 = 2.f*s1*s3;
        const float b20 = s2*s2, b21 = 2.f*s2*s3, b22 = s3*s3;
        const float4 xv = sXn[s];
        const int base = t*NSC + s*CW + c0;
        float4* PM123 = (float4*)(ws + PM123OFF);
        float2* PM0   = (float2*)(ws + PM0OFF);
        PM123[base+0] = make_float4(s2*xv.x + s3*u1.x,
                                    b10*xv.x + b11*u1.x + b12*u2.x,
                                    b20*xv.x + b21*u1.x + b22*u2.x, 0.f);
        PM123[base+1] = make_float4(s2*xv.y + s3*u1.y,
                                    b10*xv.y + b11*u1.y + b12*u2.y,
                                    b20*xv.y + b21*u1.y + b22*u2.y, 0.f);
        PM123[base+2] = make_float4(s2*xv.z + s3*u1.z,
                                    b10*xv.z + b11*u1.z + b12*u2.z,
                                    b20*xv.z + b21*u1.z + b22*u2.z, 0.f);
        PM123[base+3] = make_float4(s2*xv.w + s3*u1.w,
                                    b10*xv.w + b11*u1.w + b12*u2.w,
                                    b20*xv.w + b21*u1.w + b22*u2.w, 0.f);
        PM0[base+0] = make_float2(s0*xv.x + s1*u1.x, b00*xv.x + b01*u1.x + b02*u2.x);
        PM0[base+1] = make_float2(s0*xv.y + s1*u1.y, b00*xv.y + b01*u1.y + b02*u2.y);
        PM0[base+2] = make_float2(s0*xv.z + s1*u1.z, b00*xv.z + b01*u1.z + b02*u2.z);
        PM0[base+3] = make_float2(s0*xv.w + s1*u1.w, b00*xv.w + b01*u1.w + b02*u2.w);
    }
}

// ---------------- kB: temporal dots + epilogue (+ final out for last) -----
__global__ __launch_bounds__(256)
void kB(const float* __restrict__ xin, const float* __restrict__ H,
        const float* __restrict__ mW1, const float* __restrict__ mb1,
        const float* __restrict__ mW2, const float* __restrict__ mb2,
        const float* __restrict__ Wl, const float* __restrict__ bl,
        float* __restrict__ ws, float* __restrict__ out, int b, int last) {
    __shared__ float sAt[2*TT*TT];     // At-hat, At-hat^2
    __shared__ float sH[3*CW*CW];
    __shared__ float sW1[(CW+CIN)*CW];
    __shared__ float sW2[CW*CW];
    __shared__ float sb1[CW], sb2[CW];
    __shared__ float sx[256], sp1[256], sp2[256], sxt[256], sh[256];
    __shared__ float sxin[8*CIN];

    const int tid = threadIdx.x;
    const int gid = blockIdx.x*256 + tid;
    const int t = gid / NSC;           // block-uniform
    const int sc = gid - t*NSC;
    const int r = tid >> 5, c = tid & 31;
    const int node = gid >> 5;

    const float* Hb = H   + b*3*CW*CW;
    const float* W1 = mW1 + b*(CW+CIN)*CW;
    const float* W2 = mW2 + b*CW*CW;

    for (int i = tid; i < 2*TT*TT; i += 256) sAt[i] = ws[ATOFF + i];
    for (int i = tid; i < 3*CW*CW; i += 256) sH[i] = Hb[i];
    for (int i = tid; i < (CW+CIN)*CW; i += 256) sW1[i] = W1[i];
    for (int i = tid; i < CW*CW; i += 256) sW2[i] = W2[i];
    if (tid < CW) { sb1[tid] = mb1[b*CW + tid]; sb2[tid] = mb2[b*CW + tid]; }
    sx[tid] = ws[XOFF + gid];
    if (c < CIN) sxin[r*CIN + c] = xin[node*CIN + c];
    __syncthreads();

    {
        const float4* PM123 = (const float4*)(ws + PM123OFF);
        const float2* PM0   = (const float2*)(ws + PM0OFF);
        float d1 = 0.f, d2 = 0.f, d3 = 0.f;
        #pragma unroll
        for (int tp = 0; tp < TT; ++tp) {
            const float a1 = sAt[t*TT + tp];
            const float a2 = sAt[TT*TT + t*TT + tp];
            const float4 m = PM123[tp*NSC + sc];
            d1 += a1 * m.x;
            d2 += a1 * m.y;
            d3 += a2 * m.z;
        }
        const float2 m0 = PM0[gid];
        sp1[tid] = m0.x + d1;
        sp2[tid] = m0.y + d2 + d3;
    }
    __syncthreads();
    {
        float acc = 0.f;
        #pragma unroll 8
        for (int cp = 0; cp < CW; ++cp) {
            acc += sx[r*CW + cp]  * sH[cp*CW + c];
            acc += sp1[r*CW + cp] * sH[CW*CW + cp*CW + c];
            acc += sp2[r*CW + cp] * sH[2*CW*CW + cp*CW + c];
        }
        sxt[tid] = tanhf(acc);
    }
    __syncthreads();
    {
        float h = sb1[c];
        #pragma unroll 8
        for (int cp = 0; cp < CW; ++cp) h += sxt[r*CW + cp] * sW1[cp*CW + c];
        #pragma unroll
        for (int i = 0; i < CIN; ++i) h += sxin[r*CIN + i] * sW1[(CW+i)*CW + c];
        sh[tid] = fmaxf(h, 0.f);
    }
    __syncthreads();
    {
        float xn = sb2[c];
        #pragma unroll 8
        for (int cp = 0; cp < CW; ++cp) xn += sh[r*CW + cp] * sW2[cp*CW + c];
        if (!last) {
            ws[XOFF + gid] = xn;
        } else {
            float v = xn * Wl[c];
            #pragma unroll
            for (int off = 16; off; off >>= 1) v += __shfl_xor(v, off, 64);
            if (c == 0) out[node] = v + bl[0];
        }
    }
}

extern "C" void kernel_launch(void* const* d_in, const int* in_sizes, int n_in,
                              void* d_out, int out_size, void* d_ws, size_t ws_size,
                              hipStream_t stream) {
    const float* xin   = (const float*)d_in[0];
    const float* Adj_t = (const float*)d_in[1];
    const float* Adj_s = (const float*)d_in[2];
    const float* H     = (const float*)d_in[3];
    const float* svec  = (const float*)d_in[4];
    const float* Wf    = (const float*)d_in[5];
    const float* bf    = (const float*)d_in[6];
    const float* Wl    = (const float*)d_in[7];
    const float* bl    = (const float*)d_in[8];
    const float* mW1   = (const float*)d_in[9];
    const float* mb1   = (const float*)d_in[10];
    const float* mW2   = (const float*)d_in[11];
    const float* mb2   = (const float*)d_in[12];
    float* out = (float*)d_out;
    float* ws  = (float*)d_ws;

    kSp<true><<<193, 1024, 0, stream>>>(xin, Adj_t, Adj_s, Wf, bf, svec, ws, 0);
    kB<<<600, 256, 0, stream>>>(xin, H, mW1, mb1, mW2, mb2, Wl, bl,
                                ws, out, 0, 0);
    kSp<false><<<192, 1024, 0, stream>>>(xin, Adj_t, Adj_s, Wf, bf, svec, ws, 1);
    kB<<<600, 256, 0, stream>>>(xin, H, mW1, mb1, mW2, mb2, Wl, bl,
                                ws, out, 1, 1);
}

// Round 13
// 52.931 us; speedup vs baseline: 4.8741x; 1.0947x over previous
//
#include <hip/hip_runtime.h>
#include <math.h>

#define TT 24
#define SS 200
#define CIN 8
#define CW 32
#define NSC 6400      // SS*CW
#define NTOT 153600   // TT*SS*CW

// ws layout (float offsets)
#define DSOFF   0        // dinv_s [200]
#define ATOFF   256      // At-hat [576]
#define AT2OFF  832      // At-hat^2 [576]  (contiguous after ATOFF)
#define XOFF    1408     // X [153600]
#define M0AOFF  155008
#define M0BOFF  308608
#define M1OFF   462208
#define M2OFF   615808
#define M3OFF   769408   // end 923008 floats ~3.69 MB

// ---------------- kSp: spatial passes, one block = (t, 4-channel group) ----
// U1 = As-hat X, U2 = As-hat U1 computed sequentially in-block. 1024 thr:
// thread=(q,s); each dot split 4-way over sp with LDS partial reduce.
// As reads coalesced via symmetry (As[sp*SS+s]); sXd[sp] reads are
// uniform-address broadcasts (free). FIRST also computes X = xin@Wf+bf;
// block 192 does At-hat/At-hat^2 prep.
// NOTE R12 lesson: separate scalar M arrays beat packed-float4 (packing
// inflated bytes 288->384 per kB thread; bytes > instruction count here).
template<bool FIRST>
__global__ __launch_bounds__(1024)
void kSp(const float* __restrict__ xin, const float* __restrict__ At,
         const float* __restrict__ As, const float* __restrict__ Wf,
         const float* __restrict__ bf, const float* __restrict__ svec,
         float* __restrict__ ws, int b)
{
    __shared__ float4 sXd[SS];        // d_sp * X[sp, c0..c0+3]
    __shared__ float4 sX[SS];         // X
    __shared__ float4 sU[SS];         // d_s * U1
    __shared__ float4 spart[4][SS];   // partial sums
    __shared__ float  sd[256];
    __shared__ float  sdt[TT];
    __shared__ float  sAt[TT*TT];

    const int tid = threadIdx.x;

    if (FIRST && blockIdx.x == 192) {
        if (tid < TT) {
            float sum = 0.f;
            #pragma unroll
            for (int i = 0; i < TT; ++i) sum += At[i*TT + tid];
            sdt[tid] = 1.f / sqrtf(sum);
        }
        __syncthreads();
        if (tid < TT*TT) {
            const int i = tid / TT, j = tid % TT;
            const float v = At[tid] * sdt[i] * sdt[j] * 0.5f;
            sAt[tid] = v;
            ws[ATOFF + tid] = v;
        }
        __syncthreads();
        if (tid < TT*TT) {
            const int i = tid / TT, j = tid % TT;
            float acc = 0.f;
            #pragma unroll
            for (int k = 0; k < TT; ++k) acc += sAt[i*TT + k] * sAt[k*TT + j];
            ws[AT2OFF + tid] = acc;
        }
        return;
    }

    const int q = tid >> 8;          // 0..3 (sp quarter)
    const int s = tid & 255;         // spatial row; active if <200
    const bool act = s < SS;
    const int t  = blockIdx.x >> 3;
    const int c0 = (blockIdx.x & 7) * 4;

    // ---- dinv_s ----
    if (FIRST) {
        if (act) {
            float v = 0.f;
            #pragma unroll 5
            for (int i = q*50; i < q*50 + 50; ++i) v += As[i*SS + s];
            spart[q][s].x = v;
        }
        __syncthreads();
        if (q == 0 && act) {
            const float sum = spart[0][s].x + spart[1][s].x
                            + spart[2][s].x + spart[3][s].x;
            const float d = 1.f / sqrtf(sum);
            sd[s] = d;
            if (blockIdx.x == 0) ws[DSOFF + s] = d;
        }
        __syncthreads();
    } else {
        if (tid < SS) sd[tid] = ws[DSOFF + tid];
        __syncthreads();
    }

    // ---- stage X (+ compute it if FIRST) ----
    if (q == 0 && act) {
        float4 xv;
        if (FIRST) {
            const float4* xr = (const float4*)(xin + (t*SS + s)*CIN);
            const float4 xa = xr[0], xb = xr[1];
            float a0 = bf[c0], a1 = bf[c0+1], a2 = bf[c0+2], a3 = bf[c0+3];
            const float xi[8] = {xa.x, xa.y, xa.z, xa.w, xb.x, xb.y, xb.z, xb.w};
            #pragma unroll
            for (int i = 0; i < CIN; ++i) {
                a0 += xi[i] * Wf[i*CW + c0];
                a1 += xi[i] * Wf[i*CW + c0+1];
                a2 += xi[i] * Wf[i*CW + c0+2];
                a3 += xi[i] * Wf[i*CW + c0+3];
            }
            xv = make_float4(a0, a1, a2, a3);
            *(float4*)(ws + XOFF + t*NSC + s*CW + c0) = xv;
        } else {
            xv = *(const float4*)(ws + XOFF + t*NSC + s*CW + c0);
        }
        sX[s] = xv;
        const float d = sd[s];
        sXd[s] = make_float4(xv.x*d, xv.y*d, xv.z*d, xv.w*d);
    }
    __syncthreads();

    // ---- U1 = 0.5 d_s sum_sp As[sp,s] * (d_sp X[sp,:]) ----
    if (act) {
        float4 acc = make_float4(0.f, 0.f, 0.f, 0.f);
        #pragma unroll 5
        for (int sp = q*50; sp < q*50 + 50; ++sp) {
            const float a = As[sp*SS + s];
            const float4 xd = sXd[sp];
            acc.x += a*xd.x; acc.y += a*xd.y; acc.z += a*xd.z; acc.w += a*xd.w;
        }
        spart[q][s] = acc;
    }
    __syncthreads();
    float4 u1 = make_float4(0.f, 0.f, 0.f, 0.f);
    if (q == 0 && act) {
        const float4 p0 = spart[0][s], p1 = spart[1][s];
        const float4 p2 = spart[2][s], p3 = spart[3][s];
        const float h = 0.5f * sd[s];
        u1 = make_float4((p0.x+p1.x+p2.x+p3.x)*h, (p0.y+p1.y+p2.y+p3.y)*h,
                         (p0.z+p1.z+p2.z+p3.z)*h, (p0.w+p1.w+p2.w+p3.w)*h);
        const float d = sd[s];
        sU[s] = make_float4(u1.x*d, u1.y*d, u1.z*d, u1.w*d);
    }
    __syncthreads();

    // ---- U2 = 0.5 d_s sum_sp As[sp,s] * (d_sp U1[sp,:]) ----
    if (act) {
        float4 acc = make_float4(0.f, 0.f, 0.f, 0.f);
        #pragma unroll 5
        for (int sp = q*50; sp < q*50 + 50; ++sp) {
            const float a = As[sp*SS + s];
            const float4 ud = sU[sp];
            acc.x += a*ud.x; acc.y += a*ud.y; acc.z += a*ud.z; acc.w += a*ud.w;
        }
        spart[q][s] = acc;
    }
    __syncthreads();
    if (q == 0 && act) {
        const float4 p0 = spart[0][s], p1 = spart[1][s];
        const float4 p2 = spart[2][s], p3 = spart[3][s];
        const float h = 0.5f * sd[s];
        const float4 u2 = make_float4((p0.x+p1.x+p2.x+p3.x)*h, (p0.y+p1.y+p2.y+p3.y)*h,
                                      (p0.z+p1.z+p2.z+p3.z)*h, (p0.w+p1.w+p2.w+p3.w)*h);
        const float s0 = svec[b*4+0], s1 = svec[b*4+1];
        const float s2 = svec[b*4+2], s3 = svec[b*4+3];
        const float b00 = s0*s0, b01 = 2.f*s0*s1, b02 = s1*s1;
        const float b10 = 2.f*s0*s2, b11 = 2.f*(s0*s3 + s1*s2), b12 = 2.f*s1*s3;
        const float b20 = s2*s2, b21 = 2.f*s2*s3, b22 = s3*s3;
        const float4 xv = sX[s];
        const int gid = t*NSC + s*CW + c0;
        *(float4*)(ws + M0AOFF + gid) = make_float4(
            s0*xv.x + s1*u1.x, s0*xv.y + s1*u1.y,
            s0*xv.z + s1*u1.z, s0*xv.w + s1*u1.w);
        *(float4*)(ws + M0BOFF + gid) = make_float4(
            b00*xv.x + b01*u1.x + b02*u2.x, b00*xv.y + b01*u1.y + b02*u2.y,
            b00*xv.z + b01*u1.z + b02*u2.z, b00*xv.w + b01*u1.w + b02*u2.w);
        *(float4*)(ws + M1OFF + gid) = make_float4(
            s2*xv.x + s3*u1.x, s2*xv.y + s3*u1.y,
            s2*xv.z + s3*u1.z, s2*xv.w + s3*u1.w);
        *(float4*)(ws + M2OFF + gid) = make_float4(
            b10*xv.x + b11*u1.x + b12*u2.x, b10*xv.y + b11*u1.y + b12*u2.y,
            b10*xv.z + b11*u1.z + b12*u2.z, b10*xv.w + b11*u1.w + b12*u2.w);
        *(float4*)(ws + M3OFF + gid) = make_float4(
            b20*xv.x + b21*u1.x + b22*u2.x, b20*xv.y + b21*u1.y + b22*u2.y,
            b20*xv.z + b21*u1.z + b22*u2.z, b20*xv.w + b21*u1.w + b22*u2.w);
    }
}

// ---------------- kB: temporal dots + epilogue (+ final out for last) -----
__global__ __launch_bounds__(256)
void kB(const float* __restrict__ xin, const float* __restrict__ H,
        const float* __restrict__ mW1, const float* __restrict__ mb1,
        const float* __restrict__ mW2, const float* __restrict__ mb2,
        const float* __restrict__ Wl, const float* __restrict__ bl,
        float* __restrict__ ws, float* __restrict__ out, int b, int last) {
    __shared__ float sAt[2*TT*TT];     // At-hat, At-hat^2
    __shared__ float sH[3*CW*CW];
    __shared__ float sW1[(CW+CIN)*CW];
    __shared__ float sW2[CW*CW];
    __shared__ float sb1[CW], sb2[CW];
    __shared__ float sx[256], sp1[256], sp2[256], sxt[256], sh[256];
    __shared__ float sxin[8*CIN];

    const int tid = threadIdx.x;
    const int gid = blockIdx.x*256 + tid;
    const int t = gid / NSC;           // block-uniform
    const int sc = gid - t*NSC;
    const int r = tid >> 5, c = tid & 31;
    const int node = gid >> 5;

    const float* Hb = H   + b*3*CW*CW;
    const float* W1 = mW1 + b*(CW+CIN)*CW;
    const float* W2 = mW2 + b*CW*CW;

    for (int i = tid; i < 2*TT*TT; i += 256) sAt[i] = ws[ATOFF + i];
    for (int i = tid; i < 3*CW*CW; i += 256) sH[i] = Hb[i];
    for (int i = tid; i < (CW+CIN)*CW; i += 256) sW1[i] = W1[i];
    for (int i = tid; i < CW*CW; i += 256) sW2[i] = W2[i];
    if (tid < CW) { sb1[tid] = mb1[b*CW + tid]; sb2[tid] = mb2[b*CW + tid]; }
    sx[tid] = ws[XOFF + gid];
    if (c < CIN) sxin[r*CIN + c] = xin[node*CIN + c];
    __syncthreads();

    {
        const float* M1 = ws + M1OFF + sc;
        const float* M2 = ws + M2OFF + sc;
        const float* M3 = ws + M3OFF + sc;
        float d1 = 0.f, d2 = 0.f, d3 = 0.f;
        #pragma unroll
        for (int tp = 0; tp < TT; ++tp) {
            const float a1 = sAt[t*TT + tp];
            const float a2 = sAt[TT*TT + t*TT + tp];
            d1 += a1 * M1[tp*NSC];
            d2 += a1 * M2[tp*NSC];
            d3 += a2 * M3[tp*NSC];
        }
        sp1[tid] = ws[M0AOFF + gid] + d1;
        sp2[tid] = ws[M0BOFF + gid] + d2 + d3;
    }
    __syncthreads();
    {
        float acc = 0.f;
        #pragma unroll 8
        for (int cp = 0; cp < CW; ++cp) {
            acc += sx[r*CW + cp]  * sH[cp*CW + c];
            acc += sp1[r*CW + cp] * sH[CW*CW + cp*CW + c];
            acc += sp2[r*CW + cp] * sH[2*CW*CW + cp*CW + c];
        }
        sxt[tid] = tanhf(acc);
    }
    __syncthreads();
    {
        float h = sb1[c];
        #pragma unroll 8
        for (int cp = 0; cp < CW; ++cp) h += sxt[r*CW + cp] * sW1[cp*CW + c];
        #pragma unroll
        for (int i = 0; i < CIN; ++i) h += sxin[r*CIN + i] * sW1[(CW+i)*CW + c];
        sh[tid] = fmaxf(h, 0.f);
    }
    __syncthreads();
    {
        float xn = sb2[c];
        #pragma unroll 8
        for (int cp = 0; cp < CW; ++cp) xn += sh[r*CW + cp] * sW2[cp*CW + c];
        if (!last) {
            ws[XOFF + gid] = xn;
        } else {
            float v = xn * Wl[c];
            #pragma unroll
            for (int off = 16; off; off >>= 1) v += __shfl_xor(v, off, 64);
            if (c == 0) out[node] = v + bl[0];
        }
    }
}

extern "C" void kernel_launch(void* const* d_in, const int* in_sizes, int n_in,
                              void* d_out, int out_size, void* d_ws, size_t ws_size,
                              hipStream_t stream) {
    const float* xin   = (const float*)d_in[0];
    const float* Adj_t = (const float*)d_in[1];
    const float* Adj_s = (const float*)d_in[2];
    const float* H     = (const float*)d_in[3];
    const float* svec  = (const float*)d_in[4];
    const float* Wf    = (const float*)d_in[5];
    const float* bf    = (const float*)d_in[6];
    const float* Wl    = (const float*)d_in[7];
    const float* bl    = (const float*)d_in[8];
    const float* mW1   = (const float*)d_in[9];
    const float* mb1   = (const float*)d_in[10];
    const float* mW2   = (const float*)d_in[11];
    const float* mb2   = (const float*)d_in[12];
    float* out = (float*)d_out;
    float* ws  = (float*)d_ws;

    kSp<true><<<193, 1024, 0, stream>>>(xin, Adj_t, Adj_s, Wf, bf, svec, ws, 0);
    kB<<<600, 256, 0, stream>>>(xin, H, mW1, mb1, mW2, mb2, Wl, bl,
                                ws, out, 0, 0);
    kSp<false><<<192, 1024, 0, stream>>>(xin, Adj_t, Adj_s, Wf, bf, svec, ws, 1);
    kB<<<600, 256, 0, stream>>>(xin, H, mW1, mb1, mW2, mb2, Wl, bl,
                                ws, out, 1, 1);
}